// Round 17
// baseline (334.961 us; speedup 1.0000x reference)
//
#include <hip/hip_runtime.h>

typedef __attribute__((ext_vector_type(8))) short short8;
typedef __attribute__((ext_vector_type(4))) float f32x4;
typedef unsigned short u16;

#define T_SEQ 2048
#define C_DIM 2048

static __device__ __forceinline__ u16 f2bf(float f){
  unsigned u = __float_as_uint(f);
  u = (u + 0x7fffu + ((u >> 16) & 1u)) >> 16;
  return (u16)u;
}

// merged f32->bf16 convert for x, w_attn, w_proj
__global__ void cvt3_kernel(const float* __restrict__ x,
                            const float* __restrict__ wa,
                            const float* __restrict__ wp,
                            u16* __restrict__ xb, u16* __restrict__ wab,
                            u16* __restrict__ wpb){
  int idx = blockIdx.x * blockDim.x + threadIdx.x;
  int stride = gridDim.x * blockDim.x;
  for (int i = idx; i < 6291456; i += stride){
    const float* src; u16* dst; int j;
    if (i < 2097152){ src = x;  dst = xb;  j = i; }
    else if (i < 5242880){ src = wa; dst = wab; j = i - 2097152; }
    else { src = wp; dst = wpb; j = i - 5242880; }
    float4 v = ((const float4*)src)[j];
    ushort4 o;
    o.x = f2bf(v.x); o.y = f2bf(v.y); o.z = f2bf(v.z); o.w = f2bf(v.w);
    ((ushort4*)dst)[j] = o;
  }
}

__device__ __forceinline__ void gl_lds16(const void* g, void* l){
  __builtin_amdgcn_global_load_lds(
      (const __attribute__((address_space(1))) unsigned int*)g,
      (__attribute__((address_space(3))) unsigned int*)l,
      16, 0, 0);
}

// ------------- 128x128 BK=64 2-phase counted-vmcnt GEMM, 2 blocks/CU --------
// (round-14 verified kernel, unchanged)
template<int MODE, typename OUT>
__global__ __launch_bounds__(256, 2) void gemm256(const u16* __restrict__ A,
                                                  const u16* __restrict__ B,
                                                  OUT* __restrict__ C,
                                                  u16* __restrict__ VT,
                                                  int M, int N, int K){
  __shared__ __align__(16) u16 lA[2][128*64];   // 32 KB
  __shared__ __align__(16) u16 lB[2][128*64];   // 32 KB
  const int tid  = threadIdx.x;
  const int lane = tid & 63;
  const int r16  = lane & 15;
  const int g4   = lane >> 4;
  const int wave = tid >> 6;                 // 0..3
  const int wm = wave >> 1, wn = wave & 1;   // 2M x 2N

  const int nwg = gridDim.x * gridDim.y;
  const int idl = blockIdx.y * gridDim.x + blockIdx.x;
  const int wg  = (idl & 7) * (nwg >> 3) + (idl >> 3);
  const int bx  = wg / gridDim.y, by = wg % gridDim.y;
  const int m0 = by * 128, n0 = bx * 128;

  f32x4 acc[4][4] = {};
  const int nt = K >> 6;

  auto stA = [&](int b, int t){
    #pragma unroll
    for (int c=0;c<4;c++){
      const int row0 = wave*32 + c*8;
      const int row  = row0 + (lane>>3);
      const int cole = (((lane&7) ^ (row&7)) << 3);
      gl_lds16(&A[(size_t)(m0+row)*K + t*64 + cole], &lA[b][row0*64]);
    }
  };
  auto stB2 = [&](int b, int t, int half){
    #pragma unroll
    for (int c=0;c<2;c++){
      const int row0 = (wave>>1)*64 + half*32 + (wave&1)*16 + c*8;
      const int row  = row0 + (lane>>3);
      const int cole = (((lane&7) ^ (row&7)) << 3);
      gl_lds16(&B[(size_t)(n0+row)*K + t*64 + cole], &lB[b][row0*64]);
    }
  };
  auto rdA = [&](short8 (&af)[4][2], int b){
    #pragma unroll
    for (int i=0;i<4;i++){
      const int R = wm*64 + i*16 + r16;
      #pragma unroll
      for (int ks=0;ks<2;ks++)
        af[i][ks] = *(const short8*)&lA[b][R*64 + ((g4*8 + ks*32) ^ ((R&7)<<3))];
    }
  };
  auto rdB = [&](short8 (&bf)[2][2], int b, int half){
    #pragma unroll
    for (int j=0;j<2;j++){
      const int R = wn*64 + half*32 + j*16 + r16;
      #pragma unroll
      for (int ks=0;ks<2;ks++)
        bf[j][ks] = *(const short8*)&lB[b][R*64 + ((g4*8 + ks*32) ^ ((R&7)<<3))];
    }
  };

  stA(0,0); stB2(0,0,0); stB2(0,0,1);
  asm volatile("s_waitcnt vmcnt(2)" ::: "memory");
  __builtin_amdgcn_s_barrier();
  asm volatile("" ::: "memory");

  for (int t = 0; t < nt; ++t){
    const int cb = t & 1, nb = cb ^ 1;
    const bool more = (t + 1 < nt);
    short8 af[4][2], bf[2][2];

    rdA(af, cb); rdB(bf, cb, 0);
    if (more){
      stA(nb, t+1); stB2(nb, t+1, 0);
      asm volatile("s_waitcnt vmcnt(6)" ::: "memory");
    } else {
      asm volatile("s_waitcnt vmcnt(0)" ::: "memory");
    }
    __builtin_amdgcn_s_barrier();
    asm volatile("s_waitcnt lgkmcnt(0)" ::: "memory");
    __builtin_amdgcn_sched_barrier(0);
    __builtin_amdgcn_s_setprio(1);
    #pragma unroll
    for (int i=0;i<4;i++)
      #pragma unroll
      for (int j=0;j<2;j++)
        #pragma unroll
        for (int ks=0;ks<2;ks++)
          acc[i][j] = __builtin_amdgcn_mfma_f32_16x16x32_bf16(af[i][ks], bf[j][ks], acc[i][j], 0,0,0);
    __builtin_amdgcn_s_setprio(0);
    __builtin_amdgcn_s_barrier();
    asm volatile("" ::: "memory");

    rdB(bf, cb, 1);
    if (more){
      stB2(nb, t+1, 1);
      asm volatile("s_waitcnt vmcnt(2)" ::: "memory");
    }
    __builtin_amdgcn_s_barrier();
    asm volatile("s_waitcnt lgkmcnt(0)" ::: "memory");
    __builtin_amdgcn_sched_barrier(0);
    __builtin_amdgcn_s_setprio(1);
    #pragma unroll
    for (int i=0;i<4;i++)
      #pragma unroll
      for (int j=0;j<2;j++)
        #pragma unroll
        for (int ks=0;ks<2;ks++)
          acc[i][2+j] = __builtin_amdgcn_mfma_f32_16x16x32_bf16(af[i][ks], bf[j][ks], acc[i][2+j], 0,0,0);
    __builtin_amdgcn_s_setprio(0);
    __builtin_amdgcn_s_barrier();
    asm volatile("" ::: "memory");
  }

  if (MODE == 1 && n0 >= 4096){
    #pragma unroll
    for (int i=0;i<4;i++){
      const int m = m0 + wm*64 + i*16 + g4*4;
      const int bb = m >> 11, tt = m & 2047;
      #pragma unroll
      for (int j=0;j<4;j++){
        const int cv = n0 + wn*64 + j*16 + r16 - 4096;
        const int h = cv >> 7, dl = cv & 127;
        ushort4 pack;
        pack.x = f2bf(acc[i][j][0]); pack.y = f2bf(acc[i][j][1]);
        pack.z = f2bf(acc[i][j][2]); pack.w = f2bf(acc[i][j][3]);
        *(ushort4*)&VT[(size_t)((bb<<4) + h)*262144 + (size_t)dl*2048 + tt] = pack;
      }
    }
  } else {
    const int ldc = (MODE == 1) ? 4096 : N;
    #pragma unroll
    for (int i=0;i<4;i++){
      const int row = m0 + wm*64 + i*16 + g4*4;
      #pragma unroll
      for (int j=0;j<4;j++){
        const int col = n0 + wn*64 + j*16 + r16;
        #pragma unroll
        for (int r=0;r<4;r++){
          float v = acc[i][j][r];
          if constexpr (sizeof(OUT)==2) C[(size_t)(row+r)*ldc + col] = (OUT)f2bf(v);
          else                          C[(size_t)(row+r)*ldc + col] = (OUT)v;
        }
      }
    }
  }
}

// ---------------- Balanced-causal flash attention, V direct-from-global -----
// Each block: two 64-row q-tiles (a, 31-a) of one head; frag0 active iff t<=a
// -> constant 33 tile-units/block. LDS holds only K (double-buffered) and P:
// 48KB -> multi-block/CU residency. V fragments are contiguous 16B global
// loads from vt[d][t] (bit-identical data to the old LDS path), issued as two
// register batches: vA before QK^T (hidden under MFMA+softmax), vB before the
// first PV half (hidden under it). All register arrays statically indexed.
__global__ __launch_bounds__(256) void attn_kernel(const u16* __restrict__ qk,
                                                   const u16* __restrict__ vt,
                                                   u16* __restrict__ y){
  __shared__ __align__(16) u16 Kl[2][64*128];   // 32 KB
  __shared__ __align__(16) u16 Pl[4][32*64];    // 16 KB

  const int tid = threadIdx.x, lane = tid & 63, wave = tid >> 6;
  const int r16 = lane & 15, g4 = lane >> 4;

  const int id = blockIdx.x;            // 0..511
  const int xk = id & 7,  kk = id >> 3;
  const int bh = 4*xk + (kk & 3);       // XCD-local heads
  const int a  = kk >> 2;               // 0..15
  const int bq = 31 - a;

  const int bb = bh >> 4, h = bh & 15;
  const int qcol = h*128, kcol = 2048 + h*128;
  const u16* vhead = vt + (size_t)bh * 262144;
  const float scale = 0.08838834764831845f;

  short8 qf0[4], qf1[4];
  {
    const u16* qp0 = qk + (size_t)(bb*T_SEQ + a*64  + wave*16 + r16)*4096 + qcol;
    const u16* qp1 = qk + (size_t)(bb*T_SEQ + bq*64 + wave*16 + r16)*4096 + qcol;
    #pragma unroll
    for (int c=0;c<4;c++){
      qf0[c] = *(const short8*)&qp0[g4*8 + c*32];
      qf1[c] = *(const short8*)&qp1[g4*8 + c*32];
    }
  }

  float m0r[4], m1r[4], l0r[4], l1r[4];
  #pragma unroll
  for (int r=0;r<4;r++){ m0r[r] = -1e30f; m1r[r] = -1e30f; l0r[r] = 0.f; l1r[r] = 0.f; }
  f32x4 o0[8] = {}, o1[8] = {};

  const int nt = bq + 1;

  auto stage = [&](int sbuf, int t){   // K only
    const size_t kbase = (size_t)(bb*T_SEQ + t*64)*4096 + kcol;
    #pragma unroll
    for (int c=0;c<4;c++){
      const int row0 = wave*16 + c*4;
      const int row  = row0 + g4;
      gl_lds16(&qk[kbase + (size_t)row*4096 + ((r16*8) ^ ((row&7)<<3))],
               &Kl[sbuf][row0*128]);
    }
  };

  stage(0, 0);
  int cur = 0;

  for (int t = 0; t < nt; ++t){
    __syncthreads();
    if (t + 1 < nt) stage(cur^1, t+1);
    const bool act0 = (t <= a);   // block-uniform

    // ---- V batch A (cols 0..3): global loads issued early, used in PV
    short8 vA[4][2];
    {
      const u16* vp0 = vhead + (size_t)r16*2048 + t*64 + g4*8;
      #pragma unroll
      for (int n=0;n<4;n++){
        vA[n][0] = *(const short8*)(vp0 + (size_t)n*16*2048);
        vA[n][1] = *(const short8*)(vp0 + (size_t)n*16*2048 + 32);
      }
    }

    float s0m[4][4], s1m[4][4];
    #pragma unroll
    for (int cc=0;cc<4;cc++){
      const int krow = cc*16 + r16;
      const int sw = (krow & 7) << 3;
      short8 kf[4];
      #pragma unroll
      for (int dc=0;dc<4;dc++)
        kf[dc] = *(const short8*)&Kl[cur][krow*128 + ((g4*8 + dc*32) ^ sw)];
      {
        f32x4 sv = {0.f,0.f,0.f,0.f};
        #pragma unroll
        for (int dc=0;dc<4;dc++)
          sv = __builtin_amdgcn_mfma_f32_16x16x32_bf16(qf1[dc], kf[dc], sv, 0,0,0);
        #pragma unroll
        for (int rr=0;rr<4;rr++) s1m[cc][rr] = sv[rr] * scale;
      }
      if (act0){
        f32x4 sv = {0.f,0.f,0.f,0.f};
        #pragma unroll
        for (int dc=0;dc<4;dc++)
          sv = __builtin_amdgcn_mfma_f32_16x16x32_bf16(qf0[dc], kf[dc], sv, 0,0,0);
        #pragma unroll
        for (int rr=0;rr<4;rr++) s0m[cc][rr] = sv[rr] * scale;
      }
    }
    // diagonal masks (block-uniform branches)
    if (t == a){
      #pragma unroll
      for (int cc=0;cc<4;cc++){
        const int kvl = cc*16 + r16;
        #pragma unroll
        for (int rr=0;rr<4;rr++){
          const int qi = wave*16 + g4*4 + rr;
          if (kvl > qi) s0m[cc][rr] = -1e30f;
        }
      }
    }
    if (t == bq){
      #pragma unroll
      for (int cc=0;cc<4;cc++){
        const int kvl = cc*16 + r16;
        #pragma unroll
        for (int rr=0;rr<4;rr++){
          const int qi = wave*16 + g4*4 + rr;
          if (kvl > qi) s1m[cc][rr] = -1e30f;
        }
      }
    }

    // ---- defer-max softmax (all static indices)
    float lm0[4], lm1[4];
    #pragma unroll
    for (int rr=0;rr<4;rr++)
      lm1[rr] = fmaxf(fmaxf(s1m[0][rr], s1m[1][rr]), fmaxf(s1m[2][rr], s1m[3][rr]));
    if (act0)
      #pragma unroll
      for (int rr=0;rr<4;rr++)
        lm0[rr] = fmaxf(fmaxf(s0m[0][rr], s0m[1][rr]), fmaxf(s0m[2][rr], s0m[3][rr]));
    bool need = false;
    #pragma unroll
    for (int rr=0;rr<4;rr++) need = need || (lm1[rr] > m1r[rr] + 8.f);
    if (act0)
      #pragma unroll
      for (int rr=0;rr<4;rr++) need = need || (lm0[rr] > m0r[rr] + 8.f);
    if (__any(need)){
      #pragma unroll
      for (int rr=0;rr<4;rr++){
        float pmv = lm1[rr];
        #pragma unroll
        for (int off=1; off<16; off<<=1) pmv = fmaxf(pmv, __shfl_xor(pmv, off, 64));
        const float mnew = fmaxf(m1r[rr], pmv);
        const float corr = __expf(m1r[rr] - mnew);
        m1r[rr] = mnew;
        l1r[rr] *= corr;
        #pragma unroll
        for (int n=0;n<8;n++) o1[n][rr] *= corr;
      }
      if (act0){
        #pragma unroll
        for (int rr=0;rr<4;rr++){
          float pmv = lm0[rr];
          #pragma unroll
          for (int off=1; off<16; off<<=1) pmv = fmaxf(pmv, __shfl_xor(pmv, off, 64));
          const float mnew = fmaxf(m0r[rr], pmv);
          const float corr = __expf(m0r[rr] - mnew);
          m0r[rr] = mnew;
          l0r[rr] *= corr;
          #pragma unroll
          for (int n=0;n<8;n++) o0[n][rr] *= corr;
        }
      }
    }
    #pragma unroll
    for (int rr=0;rr<4;rr++){
      float s0 = 0.f;
      #pragma unroll
      for (int cc=0;cc<4;cc++){
        const float p = __expf(s1m[cc][rr] - m1r[rr]);
        s1m[cc][rr] = p;
        s0 += p;
      }
      #pragma unroll
      for (int off=1; off<16; off<<=1) s0 += __shfl_xor(s0, off, 64);
      l1r[rr] += s0;
    }
    if (act0){
      #pragma unroll
      for (int rr=0;rr<4;rr++){
        float s0 = 0.f;
        #pragma unroll
        for (int cc=0;cc<4;cc++){
          const float p = __expf(s0m[cc][rr] - m0r[rr]);
          s0m[cc][rr] = p;
          s0 += p;
        }
        #pragma unroll
        for (int off=1; off<16; off<<=1) s0 += __shfl_xor(s0, off, 64);
        l0r[rr] += s0;
      }
    }

    // ---- P -> LDS (frag1 -> rows 16..31, frag0 -> rows 0..15)
    #pragma unroll
    for (int cc=0;cc<4;cc++)
      #pragma unroll
      for (int rr=0;rr<4;rr++){
        const int qr = 16 + g4*4 + rr;
        Pl[wave][qr*64 + ((cc*16 + r16) ^ ((qr&7)<<3))] = f2bf(s1m[cc][rr]);
      }
    if (act0){
      #pragma unroll
      for (int cc=0;cc<4;cc++)
        #pragma unroll
        for (int rr=0;rr<4;rr++){
          const int qr = g4*4 + rr;
          Pl[wave][qr*64 + ((cc*16 + r16) ^ ((qr&7)<<3))] = f2bf(s0m[cc][rr]);
        }
    }
    asm volatile("s_waitcnt lgkmcnt(0)" ::: "memory");

    short8 pf0[2], pf1[2];
    {
      const int qr1 = 16 + r16;
      const int sw1 = (qr1 & 7) << 3;
      pf1[0] = *(const short8*)&Pl[wave][qr1*64 + ((g4*8)      ^ sw1)];
      pf1[1] = *(const short8*)&Pl[wave][qr1*64 + ((g4*8 + 32) ^ sw1)];
      if (act0){
        const int qr0 = r16;
        const int sw0 = (qr0 & 7) << 3;
        pf0[0] = *(const short8*)&Pl[wave][qr0*64 + ((g4*8)      ^ sw0)];
        pf0[1] = *(const short8*)&Pl[wave][qr0*64 + ((g4*8 + 32) ^ sw0)];
      }
    }

    // ---- V batch B (cols 4..7) issued, then PV on batch A, then batch B
    short8 vB[4][2];
    {
      const u16* vp0 = vhead + (size_t)(64 + r16)*2048 + t*64 + g4*8;
      #pragma unroll
      for (int n=0;n<4;n++){
        vB[n][0] = *(const short8*)(vp0 + (size_t)n*16*2048);
        vB[n][1] = *(const short8*)(vp0 + (size_t)n*16*2048 + 32);
      }
    }
    #pragma unroll
    for (int n=0;n<4;n++){
      o1[n] = __builtin_amdgcn_mfma_f32_16x16x32_bf16(pf1[0], vA[n][0], o1[n], 0,0,0);
      o1[n] = __builtin_amdgcn_mfma_f32_16x16x32_bf16(pf1[1], vA[n][1], o1[n], 0,0,0);
      if (act0){
        o0[n] = __builtin_amdgcn_mfma_f32_16x16x32_bf16(pf0[0], vA[n][0], o0[n], 0,0,0);
        o0[n] = __builtin_amdgcn_mfma_f32_16x16x32_bf16(pf0[1], vA[n][1], o0[n], 0,0,0);
      }
    }
    #pragma unroll
    for (int n=0;n<4;n++){
      o1[n+4] = __builtin_amdgcn_mfma_f32_16x16x32_bf16(pf1[0], vB[n][0], o1[n+4], 0,0,0);
      o1[n+4] = __builtin_amdgcn_mfma_f32_16x16x32_bf16(pf1[1], vB[n][1], o1[n+4], 0,0,0);
      if (act0){
        o0[n+4] = __builtin_amdgcn_mfma_f32_16x16x32_bf16(pf0[0], vB[n][0], o0[n+4], 0,0,0);
        o0[n+4] = __builtin_amdgcn_mfma_f32_16x16x32_bf16(pf0[1], vB[n][1], o0[n+4], 0,0,0);
      }
    }
    cur ^= 1;
  }

  {
    const size_t yr0 = (size_t)(bb*T_SEQ + a*64 + wave*16 + g4*4) * C_DIM + h*128;
    #pragma unroll
    for (int n=0;n<8;n++)
      #pragma unroll
      for (int rr=0;rr<4;rr++){
        const float v = o0[n][rr] / l0r[rr];
        y[yr0 + (size_t)rr*C_DIM + n*16 + r16] = f2bf(v);
      }
  }
  {
    const size_t yr1 = (size_t)(bb*T_SEQ + bq*64 + wave*16 + g4*4) * C_DIM + h*128;
    #pragma unroll
    for (int n=0;n<8;n++)
      #pragma unroll
      for (int rr=0;rr<4;rr++){
        const float v = o1[n][rr] / l1r[rr];
        y[yr1 + (size_t)rr*C_DIM + n*16 + r16] = f2bf(v);
      }
  }
}

extern "C" void kernel_launch(void* const* d_in, const int* in_sizes, int n_in,
                              void* d_out, int out_size, void* d_ws, size_t ws_size,
                              hipStream_t stream){
  const float* x  = (const float*)d_in[0];
  const float* wa = (const float*)d_in[1];
  const float* wp = (const float*)d_in[2];
  float* out = (float*)d_out;

  u16* ws  = (u16*)d_ws;
  u16* xb  = ws;                 //  8,388,608 elems (x bf16) — reused as yb later
  u16* wab = xb  + 8388608;      // 12,582,912 elems (w_attn bf16)
  u16* wpb = wab + 12582912;     //  4,194,304 elems (w_proj bf16)
  u16* qk  = wpb + 4194304;      // 16,777,216 elems ([4096][4096] Q|K)
  u16* vt  = qk  + 16777216;     //  8,388,608 elems ([32][128][2048] V^T)
  u16* yb  = xb;                 // alias: x dead after GEMM1

  hipLaunchKernelGGL(cvt3_kernel, dim3(2048), dim3(256), 0, stream,
                     x, wa, wp, xb, wab, wpb);

  // qkv projection: grid 48 n-tiles(128) x 32 m-tiles(128) = 1536 = 3 rounds @ 2/CU
  hipLaunchKernelGGL((gemm256<1,u16>),   dim3(48,32), dim3(256), 0, stream,
                     xb, wab, qk, vt, 4096, 6144, 2048);
  hipLaunchKernelGGL(attn_kernel,        dim3(512),  dim3(256), 0, stream,
                     qk, vt, yb);
  // out projection: grid 16 x 32 = 512 = 1 round @ 2/CU
  hipLaunchKernelGGL((gemm256<0,float>), dim3(16,32), dim3(256), 0, stream,
                     yb, wpb, out, (u16*)nullptr, 4096, 2048, 2048);
}

// Round 18
// 254.178 us; speedup vs baseline: 1.3178x; 1.3178x over previous
//
#include <hip/hip_runtime.h>

typedef __attribute__((ext_vector_type(8))) short short8;
typedef __attribute__((ext_vector_type(4))) float f32x4;
typedef unsigned short u16;

#define T_SEQ 2048
#define C_DIM 2048

static __device__ __forceinline__ u16 f2bf(float f){
  unsigned u = __float_as_uint(f);
  u = (u + 0x7fffu + ((u >> 16) & 1u)) >> 16;
  return (u16)u;
}

// merged f32->bf16 convert for x, w_attn, w_proj
__global__ void cvt3_kernel(const float* __restrict__ x,
                            const float* __restrict__ wa,
                            const float* __restrict__ wp,
                            u16* __restrict__ xb, u16* __restrict__ wab,
                            u16* __restrict__ wpb){
  int idx = blockIdx.x * blockDim.x + threadIdx.x;
  int stride = gridDim.x * blockDim.x;
  for (int i = idx; i < 6291456; i += stride){
    const float* src; u16* dst; int j;
    if (i < 2097152){ src = x;  dst = xb;  j = i; }
    else if (i < 5242880){ src = wa; dst = wab; j = i - 2097152; }
    else { src = wp; dst = wpb; j = i - 5242880; }
    float4 v = ((const float4*)src)[j];
    ushort4 o;
    o.x = f2bf(v.x); o.y = f2bf(v.y); o.z = f2bf(v.z); o.w = f2bf(v.w);
    ((ushort4*)dst)[j] = o;
  }
}

__device__ __forceinline__ void gl_lds16(const void* g, void* l){
  __builtin_amdgcn_global_load_lds(
      (const __attribute__((address_space(1))) unsigned int*)g,
      (__attribute__((address_space(3))) unsigned int*)l,
      16, 0, 0);
}

// ------------- 128x128 BK=64 2-phase counted-vmcnt GEMM, 2 blocks/CU --------
// (round-14 verified kernel, unchanged)
template<int MODE, typename OUT>
__global__ __launch_bounds__(256, 2) void gemm256(const u16* __restrict__ A,
                                                  const u16* __restrict__ B,
                                                  OUT* __restrict__ C,
                                                  u16* __restrict__ VT,
                                                  int M, int N, int K){
  __shared__ __align__(16) u16 lA[2][128*64];   // 32 KB
  __shared__ __align__(16) u16 lB[2][128*64];   // 32 KB
  const int tid  = threadIdx.x;
  const int lane = tid & 63;
  const int r16  = lane & 15;
  const int g4   = lane >> 4;
  const int wave = tid >> 6;                 // 0..3
  const int wm = wave >> 1, wn = wave & 1;   // 2M x 2N

  const int nwg = gridDim.x * gridDim.y;
  const int idl = blockIdx.y * gridDim.x + blockIdx.x;
  const int wg  = (idl & 7) * (nwg >> 3) + (idl >> 3);
  const int bx  = wg / gridDim.y, by = wg % gridDim.y;
  const int m0 = by * 128, n0 = bx * 128;

  f32x4 acc[4][4] = {};
  const int nt = K >> 6;

  auto stA = [&](int b, int t){
    #pragma unroll
    for (int c=0;c<4;c++){
      const int row0 = wave*32 + c*8;
      const int row  = row0 + (lane>>3);
      const int cole = (((lane&7) ^ (row&7)) << 3);
      gl_lds16(&A[(size_t)(m0+row)*K + t*64 + cole], &lA[b][row0*64]);
    }
  };
  auto stB2 = [&](int b, int t, int half){
    #pragma unroll
    for (int c=0;c<2;c++){
      const int row0 = (wave>>1)*64 + half*32 + (wave&1)*16 + c*8;
      const int row  = row0 + (lane>>3);
      const int cole = (((lane&7) ^ (row&7)) << 3);
      gl_lds16(&B[(size_t)(n0+row)*K + t*64 + cole], &lB[b][row0*64]);
    }
  };
  auto rdA = [&](short8 (&af)[4][2], int b){
    #pragma unroll
    for (int i=0;i<4;i++){
      const int R = wm*64 + i*16 + r16;
      #pragma unroll
      for (int ks=0;ks<2;ks++)
        af[i][ks] = *(const short8*)&lA[b][R*64 + ((g4*8 + ks*32) ^ ((R&7)<<3))];
    }
  };
  auto rdB = [&](short8 (&bf)[2][2], int b, int half){
    #pragma unroll
    for (int j=0;j<2;j++){
      const int R = wn*64 + half*32 + j*16 + r16;
      #pragma unroll
      for (int ks=0;ks<2;ks++)
        bf[j][ks] = *(const short8*)&lB[b][R*64 + ((g4*8 + ks*32) ^ ((R&7)<<3))];
    }
  };

  stA(0,0); stB2(0,0,0); stB2(0,0,1);
  asm volatile("s_waitcnt vmcnt(2)" ::: "memory");
  __builtin_amdgcn_s_barrier();
  asm volatile("" ::: "memory");

  for (int t = 0; t < nt; ++t){
    const int cb = t & 1, nb = cb ^ 1;
    const bool more = (t + 1 < nt);
    short8 af[4][2], bf[2][2];

    rdA(af, cb); rdB(bf, cb, 0);
    if (more){
      stA(nb, t+1); stB2(nb, t+1, 0);
      asm volatile("s_waitcnt vmcnt(6)" ::: "memory");
    } else {
      asm volatile("s_waitcnt vmcnt(0)" ::: "memory");
    }
    __builtin_amdgcn_s_barrier();
    asm volatile("s_waitcnt lgkmcnt(0)" ::: "memory");
    __builtin_amdgcn_sched_barrier(0);
    __builtin_amdgcn_s_setprio(1);
    #pragma unroll
    for (int i=0;i<4;i++)
      #pragma unroll
      for (int j=0;j<2;j++)
        #pragma unroll
        for (int ks=0;ks<2;ks++)
          acc[i][j] = __builtin_amdgcn_mfma_f32_16x16x32_bf16(af[i][ks], bf[j][ks], acc[i][j], 0,0,0);
    __builtin_amdgcn_s_setprio(0);
    __builtin_amdgcn_s_barrier();
    asm volatile("" ::: "memory");

    rdB(bf, cb, 1);
    if (more){
      stB2(nb, t+1, 1);
      asm volatile("s_waitcnt vmcnt(2)" ::: "memory");
    }
    __builtin_amdgcn_s_barrier();
    asm volatile("s_waitcnt lgkmcnt(0)" ::: "memory");
    __builtin_amdgcn_sched_barrier(0);
    __builtin_amdgcn_s_setprio(1);
    #pragma unroll
    for (int i=0;i<4;i++)
      #pragma unroll
      for (int j=0;j<2;j++)
        #pragma unroll
        for (int ks=0;ks<2;ks++)
          acc[i][2+j] = __builtin_amdgcn_mfma_f32_16x16x32_bf16(af[i][ks], bf[j][ks], acc[i][2+j], 0,0,0);
    __builtin_amdgcn_s_setprio(0);
    __builtin_amdgcn_s_barrier();
    asm volatile("" ::: "memory");
  }

  if (MODE == 1 && n0 >= 4096){
    #pragma unroll
    for (int i=0;i<4;i++){
      const int m = m0 + wm*64 + i*16 + g4*4;
      const int bb = m >> 11, tt = m & 2047;
      #pragma unroll
      for (int j=0;j<4;j++){
        const int cv = n0 + wn*64 + j*16 + r16 - 4096;
        const int h = cv >> 7, dl = cv & 127;
        ushort4 pack;
        pack.x = f2bf(acc[i][j][0]); pack.y = f2bf(acc[i][j][1]);
        pack.z = f2bf(acc[i][j][2]); pack.w = f2bf(acc[i][j][3]);
        *(ushort4*)&VT[(size_t)((bb<<4) + h)*262144 + (size_t)dl*2048 + tt] = pack;
      }
    }
  } else {
    const int ldc = (MODE == 1) ? 4096 : N;
    #pragma unroll
    for (int i=0;i<4;i++){
      const int row = m0 + wm*64 + i*16 + g4*4;
      #pragma unroll
      for (int j=0;j<4;j++){
        const int col = n0 + wn*64 + j*16 + r16;
        #pragma unroll
        for (int r=0;r<4;r++){
          float v = acc[i][j][r];
          if constexpr (sizeof(OUT)==2) C[(size_t)(row+r)*ldc + col] = (OUT)f2bf(v);
          else                          C[(size_t)(row+r)*ldc + col] = (OUT)v;
        }
      }
    }
  }
}

// ---------------- Flash attention: 8 waves x 16 q-rows, QBLK=128 ------------
// r14 pipeline (K+V LDS gl_lds staging, 2-phase, defer-max, (v,15-v) qt
// pairing) but 8 waves/block with ONE 16-row fragment per wave: halves the
// per-wave serial softmax VALU and doubles wave residency so softmax(VALU)
// overlaps other waves' MFMA (m114). All register indices static.
__global__ __launch_bounds__(512) void attn_kernel(const u16* __restrict__ qk,
                                                   const u16* __restrict__ vt,
                                                   u16* __restrict__ y){
  __shared__ __align__(16) u16 Kl[2][64*128];   // 32 KB
  __shared__ __align__(16) u16 Vl[2][128*64];   // 32 KB
  __shared__ __align__(16) u16 Pl[8][16*64];    // 16 KB

  const int tid = threadIdx.x, lane = tid & 63, wave = tid >> 6;  // 0..7
  const int r16 = lane & 15, g4 = lane >> 4;

  const int id = blockIdx.x;            // 0..511
  const int xk = id & 7,  kk = id >> 3;
  const int bh = 4*xk + (kk & 3);       // XCD-local heads
  const int v5 = kk >> 2;               // 0..15
  const int qt = (v5 < 8) ? v5 : (23 - v5);   // (v,15-v) share a CU slot

  const int bb = bh >> 4, h = bh & 15;
  const int qcol = h*128, kcol = 2048 + h*128;
  const u16* vhead = vt + (size_t)bh * 262144;
  const float scale = 0.08838834764831845f;

  short8 qf[4];
  {
    const u16* qp = qk + (size_t)(bb*T_SEQ + qt*128 + wave*16 + r16)*4096 + qcol;
    #pragma unroll
    for (int c=0;c<4;c++) qf[c] = *(const short8*)&qp[g4*8 + c*32];
  }

  float mrow[4], lrow[4];
  #pragma unroll
  for (int r=0;r<4;r++){ mrow[r] = -1e30f; lrow[r] = 0.f; }
  f32x4 o[8] = {};

  const int nt = 2*qt + 2;

  auto stage = [&](int sbuf, int t){
    const size_t kbase = (size_t)(bb*T_SEQ + t*64)*4096 + kcol;
    #pragma unroll
    for (int c=0;c<2;c++){
      const int row0 = wave*8 + c*4;        // wave-uniform; 8 waves cover 0..63
      const int row  = row0 + g4;
      gl_lds16(&qk[kbase + (size_t)row*4096 + ((r16*8) ^ ((row&7)<<3))],
               &Kl[sbuf][row0*128]);
    }
    const int t0 = t*64;
    #pragma unroll
    for (int c=0;c<2;c++){
      const int idx = wave*2 + c;           // 0..15, wave-uniform
      const int d   = idx*8 + (lane>>3);
      const int j8  = (lane&7)*8;
      gl_lds16(&vhead[(size_t)d*2048 + t0 + (j8 ^ ((d&7)<<3))],
               &Vl[sbuf][idx*512]);
    }
  };

  stage(0, 0);
  int cur = 0;

  for (int t = 0; t < nt; ++t){
    __syncthreads();
    if (t + 1 < nt) stage(cur^1, t+1);

    // ---- S = Q K^T : per wave 16q x 64kv
    float smat[4][4];
    #pragma unroll
    for (int cc=0;cc<4;cc++){
      const int krow = cc*16 + r16;
      const int sw = (krow & 7) << 3;
      short8 kf[4];
      #pragma unroll
      for (int dc=0;dc<4;dc++)
        kf[dc] = *(const short8*)&Kl[cur][krow*128 + ((g4*8 + dc*32) ^ sw)];
      f32x4 sv = {0.f,0.f,0.f,0.f};
      #pragma unroll
      for (int dc=0;dc<4;dc++)
        sv = __builtin_amdgcn_mfma_f32_16x16x32_bf16(qf[dc], kf[dc], sv, 0,0,0);
      #pragma unroll
      for (int rr=0;rr<4;rr++) smat[cc][rr] = sv[rr] * scale;
    }
    if (t >= 2*qt){   // diagonal region (block-uniform)
      #pragma unroll
      for (int cc=0;cc<4;cc++){
        const int kvl = (t - 2*qt)*64 + cc*16 + r16;
        #pragma unroll
        for (int rr=0;rr<4;rr++){
          const int qi = wave*16 + g4*4 + rr;
          if (kvl > qi) smat[cc][rr] = -1e30f;
        }
      }
    }

    // ---- defer-max softmax (local pre-check; wave-uniform branch)
    float lm[4];
    #pragma unroll
    for (int rr=0;rr<4;rr++)
      lm[rr] = fmaxf(fmaxf(smat[0][rr], smat[1][rr]), fmaxf(smat[2][rr], smat[3][rr]));
    bool need = false;
    #pragma unroll
    for (int rr=0;rr<4;rr++) need = need || (lm[rr] > mrow[rr] + 8.f);
    if (__any(need)){
      #pragma unroll
      for (int rr=0;rr<4;rr++){
        float pmv = lm[rr];
        #pragma unroll
        for (int off=1; off<16; off<<=1) pmv = fmaxf(pmv, __shfl_xor(pmv, off, 64));
        const float mnew = fmaxf(mrow[rr], pmv);
        const float corr = __expf(mrow[rr] - mnew);
        mrow[rr] = mnew;
        lrow[rr] *= corr;
        #pragma unroll
        for (int n=0;n<8;n++) o[n][rr] *= corr;
      }
    }
    #pragma unroll
    for (int rr=0;rr<4;rr++){
      float s0 = 0.f;
      #pragma unroll
      for (int cc=0;cc<4;cc++){
        const float p = __expf(smat[cc][rr] - mrow[rr]);
        smat[cc][rr] = p;
        s0 += p;
      }
      #pragma unroll
      for (int off=1; off<16; off<<=1) s0 += __shfl_xor(s0, off, 64);
      lrow[rr] += s0;
    }

    // ---- P -> LDS (wave-local 16 rows)
    #pragma unroll
    for (int cc=0;cc<4;cc++)
      #pragma unroll
      for (int rr=0;rr<4;rr++){
        const int qr = g4*4 + rr;
        Pl[wave][qr*64 + ((cc*16 + r16) ^ ((qr&7)<<3))] = f2bf(smat[cc][rr]);
      }
    asm volatile("s_waitcnt lgkmcnt(0)" ::: "memory");

    short8 pf0, pf1;
    {
      const int qr = r16;
      const int sw = (qr & 7) << 3;
      pf0 = *(const short8*)&Pl[wave][qr*64 + ((g4*8)      ^ sw)];
      pf1 = *(const short8*)&Pl[wave][qr*64 + ((g4*8 + 32) ^ sw)];
    }
    #pragma unroll
    for (int n=0;n<8;n++){
      const int vr = n*16 + r16;
      const int sw = (vr & 7) << 3;
      short8 vf0 = *(const short8*)&Vl[cur][vr*64 + ((g4*8)      ^ sw)];
      short8 vf1 = *(const short8*)&Vl[cur][vr*64 + ((g4*8 + 32) ^ sw)];
      o[n] = __builtin_amdgcn_mfma_f32_16x16x32_bf16(pf0, vf0, o[n], 0,0,0);
      o[n] = __builtin_amdgcn_mfma_f32_16x16x32_bf16(pf1, vf1, o[n], 0,0,0);
    }
    cur ^= 1;
  }

  {
    const size_t yr0 = (size_t)(bb*T_SEQ + qt*128 + wave*16 + g4*4) * C_DIM + h*128;
    #pragma unroll
    for (int n=0;n<8;n++)
      #pragma unroll
      for (int rr=0;rr<4;rr++){
        const float v = o[n][rr] / lrow[rr];
        y[yr0 + (size_t)rr*C_DIM + n*16 + r16] = f2bf(v);
      }
  }
}

extern "C" void kernel_launch(void* const* d_in, const int* in_sizes, int n_in,
                              void* d_out, int out_size, void* d_ws, size_t ws_size,
                              hipStream_t stream){
  const float* x  = (const float*)d_in[0];
  const float* wa = (const float*)d_in[1];
  const float* wp = (const float*)d_in[2];
  float* out = (float*)d_out;

  u16* ws  = (u16*)d_ws;
  u16* xb  = ws;                 //  8,388,608 elems (x bf16) — reused as yb later
  u16* wab = xb  + 8388608;      // 12,582,912 elems (w_attn bf16)
  u16* wpb = wab + 12582912;     //  4,194,304 elems (w_proj bf16)
  u16* qk  = wpb + 4194304;      // 16,777,216 elems ([4096][4096] Q|K)
  u16* vt  = qk  + 16777216;     //  8,388,608 elems ([32][128][2048] V^T)
  u16* yb  = xb;                 // alias: x dead after GEMM1

  hipLaunchKernelGGL(cvt3_kernel, dim3(2048), dim3(256), 0, stream,
                     x, wa, wp, xb, wab, wpb);

  // qkv projection: grid 48 n-tiles(128) x 32 m-tiles(128) = 1536 = 3 rounds @ 2/CU
  hipLaunchKernelGGL((gemm256<1,u16>),   dim3(48,32), dim3(256), 0, stream,
                     xb, wab, qk, vt, 4096, 6144, 2048);
  hipLaunchKernelGGL(attn_kernel,        dim3(512),  dim3(512), 0, stream,
                     qk, vt, yb);
  // out projection: grid 16 x 32 = 512 = 1 round @ 2/CU
  hipLaunchKernelGGL((gemm256<0,float>), dim3(16,32), dim3(512 / 2), 0, stream,
                     yb, wpb, out, (u16*)nullptr, 4096, 2048, 2048);
}

// Round 19
// 246.227 us; speedup vs baseline: 1.3604x; 1.0323x over previous
//
#include <hip/hip_runtime.h>

typedef __attribute__((ext_vector_type(8))) short short8;
typedef __attribute__((ext_vector_type(4))) float f32x4;
typedef unsigned short u16;

#define T_SEQ 2048
#define C_DIM 2048

static __device__ __forceinline__ u16 f2bf(float f){
  unsigned u = __float_as_uint(f);
  u = (u + 0x7fffu + ((u >> 16) & 1u)) >> 16;
  return (u16)u;
}

// merged f32->bf16 convert for x, w_attn, w_proj
__global__ void cvt3_kernel(const float* __restrict__ x,
                            const float* __restrict__ wa,
                            const float* __restrict__ wp,
                            u16* __restrict__ xb, u16* __restrict__ wab,
                            u16* __restrict__ wpb){
  int idx = blockIdx.x * blockDim.x + threadIdx.x;
  int stride = gridDim.x * blockDim.x;
  for (int i = idx; i < 6291456; i += stride){
    const float* src; u16* dst; int j;
    if (i < 2097152){ src = x;  dst = xb;  j = i; }
    else if (i < 5242880){ src = wa; dst = wab; j = i - 2097152; }
    else { src = wp; dst = wpb; j = i - 5242880; }
    float4 v = ((const float4*)src)[j];
    ushort4 o;
    o.x = f2bf(v.x); o.y = f2bf(v.y); o.z = f2bf(v.z); o.w = f2bf(v.w);
    ((ushort4*)dst)[j] = o;
  }
}

__device__ __forceinline__ void gl_lds16(const void* g, void* l){
  __builtin_amdgcn_global_load_lds(
      (const __attribute__((address_space(1))) unsigned int*)g,
      (__attribute__((address_space(3))) unsigned int*)l,
      16, 0, 0);
}

// ------------- 128x128 BK=64 2-phase counted-vmcnt GEMM, 2 blocks/CU --------
// r14 engine. r19 change: N-FASTEST XCD swizzle — each XCD owns a contiguous
// band of gridDim.x/8 n-tiles (B panels stay L2-resident for the whole
// kernel: 6x512KB=3MB for gemm1) and n varies fastest within the XCD, so
// each A-tile is fetched once and shared by npx concurrent blocks. Expected
// per-XCD fetch A 16MB + B 3MB (was A 96MB with m-fastest).
template<int MODE, typename OUT>
__global__ __launch_bounds__(256, 2) void gemm256(const u16* __restrict__ A,
                                                  const u16* __restrict__ B,
                                                  OUT* __restrict__ C,
                                                  u16* __restrict__ VT,
                                                  int M, int N, int K){
  __shared__ __align__(16) u16 lA[2][128*64];   // 32 KB
  __shared__ __align__(16) u16 lB[2][128*64];   // 32 KB
  const int tid  = threadIdx.x;
  const int lane = tid & 63;
  const int r16  = lane & 15;
  const int g4   = lane >> 4;
  const int wave = tid >> 6;                 // 0..3
  const int wm = wave >> 1, wn = wave & 1;   // 2M x 2N

  // n-fastest XCD swizzle (bijective; gridDim.x % 8 == 0)
  const int idl = blockIdx.y * gridDim.x + blockIdx.x;
  const int xcd = idl & 7, k = idl >> 3;
  const int npx = gridDim.x >> 3;            // n-tiles per XCD
  const int bx  = xcd * npx + (k % npx);
  const int by  = k / npx;
  const int m0 = by * 128, n0 = bx * 128;

  f32x4 acc[4][4] = {};
  const int nt = K >> 6;

  auto stA = [&](int b, int t){
    #pragma unroll
    for (int c=0;c<4;c++){
      const int row0 = wave*32 + c*8;
      const int row  = row0 + (lane>>3);
      const int cole = (((lane&7) ^ (row&7)) << 3);
      gl_lds16(&A[(size_t)(m0+row)*K + t*64 + cole], &lA[b][row0*64]);
    }
  };
  auto stB2 = [&](int b, int t, int half){
    #pragma unroll
    for (int c=0;c<2;c++){
      const int row0 = (wave>>1)*64 + half*32 + (wave&1)*16 + c*8;
      const int row  = row0 + (lane>>3);
      const int cole = (((lane&7) ^ (row&7)) << 3);
      gl_lds16(&B[(size_t)(n0+row)*K + t*64 + cole], &lB[b][row0*64]);
    }
  };
  auto rdA = [&](short8 (&af)[4][2], int b){
    #pragma unroll
    for (int i=0;i<4;i++){
      const int R = wm*64 + i*16 + r16;
      #pragma unroll
      for (int ks=0;ks<2;ks++)
        af[i][ks] = *(const short8*)&lA[b][R*64 + ((g4*8 + ks*32) ^ ((R&7)<<3))];
    }
  };
  auto rdB = [&](short8 (&bf)[2][2], int b, int half){
    #pragma unroll
    for (int j=0;j<2;j++){
      const int R = wn*64 + half*32 + j*16 + r16;
      #pragma unroll
      for (int ks=0;ks<2;ks++)
        bf[j][ks] = *(const short8*)&lB[b][R*64 + ((g4*8 + ks*32) ^ ((R&7)<<3))];
    }
  };

  stA(0,0); stB2(0,0,0); stB2(0,0,1);
  asm volatile("s_waitcnt vmcnt(2)" ::: "memory");
  __builtin_amdgcn_s_barrier();
  asm volatile("" ::: "memory");

  for (int t = 0; t < nt; ++t){
    const int cb = t & 1, nb = cb ^ 1;
    const bool more = (t + 1 < nt);
    short8 af[4][2], bf[2][2];

    rdA(af, cb); rdB(bf, cb, 0);
    if (more){
      stA(nb, t+1); stB2(nb, t+1, 0);
      asm volatile("s_waitcnt vmcnt(6)" ::: "memory");
    } else {
      asm volatile("s_waitcnt vmcnt(0)" ::: "memory");
    }
    __builtin_amdgcn_s_barrier();
    asm volatile("s_waitcnt lgkmcnt(0)" ::: "memory");
    __builtin_amdgcn_sched_barrier(0);
    __builtin_amdgcn_s_setprio(1);
    #pragma unroll
    for (int i=0;i<4;i++)
      #pragma unroll
      for (int j=0;j<2;j++)
        #pragma unroll
        for (int ks=0;ks<2;ks++)
          acc[i][j] = __builtin_amdgcn_mfma_f32_16x16x32_bf16(af[i][ks], bf[j][ks], acc[i][j], 0,0,0);
    __builtin_amdgcn_s_setprio(0);
    __builtin_amdgcn_s_barrier();
    asm volatile("" ::: "memory");

    rdB(bf, cb, 1);
    if (more){
      stB2(nb, t+1, 1);
      asm volatile("s_waitcnt vmcnt(2)" ::: "memory");
    }
    __builtin_amdgcn_s_barrier();
    asm volatile("s_waitcnt lgkmcnt(0)" ::: "memory");
    __builtin_amdgcn_sched_barrier(0);
    __builtin_amdgcn_s_setprio(1);
    #pragma unroll
    for (int i=0;i<4;i++)
      #pragma unroll
      for (int j=0;j<2;j++)
        #pragma unroll
        for (int ks=0;ks<2;ks++)
          acc[i][2+j] = __builtin_amdgcn_mfma_f32_16x16x32_bf16(af[i][ks], bf[j][ks], acc[i][2+j], 0,0,0);
    __builtin_amdgcn_s_setprio(0);
    __builtin_amdgcn_s_barrier();
    asm volatile("" ::: "memory");
  }

  if (MODE == 1 && n0 >= 4096){
    #pragma unroll
    for (int i=0;i<4;i++){
      const int m = m0 + wm*64 + i*16 + g4*4;
      const int bb = m >> 11, tt = m & 2047;
      #pragma unroll
      for (int j=0;j<4;j++){
        const int cv = n0 + wn*64 + j*16 + r16 - 4096;
        const int h = cv >> 7, dl = cv & 127;
        ushort4 pack;
        pack.x = f2bf(acc[i][j][0]); pack.y = f2bf(acc[i][j][1]);
        pack.z = f2bf(acc[i][j][2]); pack.w = f2bf(acc[i][j][3]);
        *(ushort4*)&VT[(size_t)((bb<<4) + h)*262144 + (size_t)dl*2048 + tt] = pack;
      }
    }
  } else {
    const int ldc = (MODE == 1) ? 4096 : N;
    #pragma unroll
    for (int i=0;i<4;i++){
      const int row = m0 + wm*64 + i*16 + g4*4;
      #pragma unroll
      for (int j=0;j<4;j++){
        const int col = n0 + wn*64 + j*16 + r16;
        #pragma unroll
        for (int r=0;r<4;r++){
          float v = acc[i][j][r];
          if constexpr (sizeof(OUT)==2) C[(size_t)(row+r)*ldc + col] = (OUT)f2bf(v);
          else                          C[(size_t)(row+r)*ldc + col] = (OUT)v;
        }
      }
    }
  }
}

// ---------------- Flash attention: 8 waves x 16 q-rows, QBLK=128 ------------
// (round-18 verified kernel, unchanged)
__global__ __launch_bounds__(512) void attn_kernel(const u16* __restrict__ qk,
                                                   const u16* __restrict__ vt,
                                                   u16* __restrict__ y){
  __shared__ __align__(16) u16 Kl[2][64*128];   // 32 KB
  __shared__ __align__(16) u16 Vl[2][128*64];   // 32 KB
  __shared__ __align__(16) u16 Pl[8][16*64];    // 16 KB

  const int tid = threadIdx.x, lane = tid & 63, wave = tid >> 6;  // 0..7
  const int r16 = lane & 15, g4 = lane >> 4;

  const int id = blockIdx.x;            // 0..511
  const int xk = id & 7,  kk = id >> 3;
  const int bh = 4*xk + (kk & 3);       // XCD-local heads
  const int v5 = kk >> 2;               // 0..15
  const int qt = (v5 < 8) ? v5 : (23 - v5);   // (v,15-v) share a CU slot

  const int bb = bh >> 4, h = bh & 15;
  const int qcol = h*128, kcol = 2048 + h*128;
  const u16* vhead = vt + (size_t)bh * 262144;
  const float scale = 0.08838834764831845f;

  short8 qf[4];
  {
    const u16* qp = qk + (size_t)(bb*T_SEQ + qt*128 + wave*16 + r16)*4096 + qcol;
    #pragma unroll
    for (int c=0;c<4;c++) qf[c] = *(const short8*)&qp[g4*8 + c*32];
  }

  float mrow[4], lrow[4];
  #pragma unroll
  for (int r=0;r<4;r++){ mrow[r] = -1e30f; lrow[r] = 0.f; }
  f32x4 o[8] = {};

  const int nt = 2*qt + 2;

  auto stage = [&](int sbuf, int t){
    const size_t kbase = (size_t)(bb*T_SEQ + t*64)*4096 + kcol;
    #pragma unroll
    for (int c=0;c<2;c++){
      const int row0 = wave*8 + c*4;        // wave-uniform; 8 waves cover 0..63
      const int row  = row0 + g4;
      gl_lds16(&qk[kbase + (size_t)row*4096 + ((r16*8) ^ ((row&7)<<3))],
               &Kl[sbuf][row0*128]);
    }
    const int t0 = t*64;
    #pragma unroll
    for (int c=0;c<2;c++){
      const int idx = wave*2 + c;           // 0..15, wave-uniform
      const int d   = idx*8 + (lane>>3);
      const int j8  = (lane&7)*8;
      gl_lds16(&vhead[(size_t)d*2048 + t0 + (j8 ^ ((d&7)<<3))],
               &Vl[sbuf][idx*512]);
    }
  };

  stage(0, 0);
  int cur = 0;

  for (int t = 0; t < nt; ++t){
    __syncthreads();
    if (t + 1 < nt) stage(cur^1, t+1);

    // ---- S = Q K^T : per wave 16q x 64kv
    float smat[4][4];
    #pragma unroll
    for (int cc=0;cc<4;cc++){
      const int krow = cc*16 + r16;
      const int sw = (krow & 7) << 3;
      short8 kf[4];
      #pragma unroll
      for (int dc=0;dc<4;dc++)
        kf[dc] = *(const short8*)&Kl[cur][krow*128 + ((g4*8 + dc*32) ^ sw)];
      f32x4 sv = {0.f,0.f,0.f,0.f};
      #pragma unroll
      for (int dc=0;dc<4;dc++)
        sv = __builtin_amdgcn_mfma_f32_16x16x32_bf16(qf[dc], kf[dc], sv, 0,0,0);
      #pragma unroll
      for (int rr=0;rr<4;rr++) smat[cc][rr] = sv[rr] * scale;
    }
    if (t >= 2*qt){   // diagonal region (block-uniform)
      #pragma unroll
      for (int cc=0;cc<4;cc++){
        const int kvl = (t - 2*qt)*64 + cc*16 + r16;
        #pragma unroll
        for (int rr=0;rr<4;rr++){
          const int qi = wave*16 + g4*4 + rr;
          if (kvl > qi) smat[cc][rr] = -1e30f;
        }
      }
    }

    // ---- defer-max softmax (local pre-check; wave-uniform branch)
    float lm[4];
    #pragma unroll
    for (int rr=0;rr<4;rr++)
      lm[rr] = fmaxf(fmaxf(smat[0][rr], smat[1][rr]), fmaxf(smat[2][rr], smat[3][rr]));
    bool need = false;
    #pragma unroll
    for (int rr=0;rr<4;rr++) need = need || (lm[rr] > mrow[rr] + 8.f);
    if (__any(need)){
      #pragma unroll
      for (int rr=0;rr<4;rr++){
        float pmv = lm[rr];
        #pragma unroll
        for (int off=1; off<16; off<<=1) pmv = fmaxf(pmv, __shfl_xor(pmv, off, 64));
        const float mnew = fmaxf(mrow[rr], pmv);
        const float corr = __expf(mrow[rr] - mnew);
        mrow[rr] = mnew;
        lrow[rr] *= corr;
        #pragma unroll
        for (int n=0;n<8;n++) o[n][rr] *= corr;
      }
    }
    #pragma unroll
    for (int rr=0;rr<4;rr++){
      float s0 = 0.f;
      #pragma unroll
      for (int cc=0;cc<4;cc++){
        const float p = __expf(smat[cc][rr] - mrow[rr]);
        smat[cc][rr] = p;
        s0 += p;
      }
      #pragma unroll
      for (int off=1; off<16; off<<=1) s0 += __shfl_xor(s0, off, 64);
      lrow[rr] += s0;
    }

    // ---- P -> LDS (wave-local 16 rows)
    #pragma unroll
    for (int cc=0;cc<4;cc++)
      #pragma unroll
      for (int rr=0;rr<4;rr++){
        const int qr = g4*4 + rr;
        Pl[wave][qr*64 + ((cc*16 + r16) ^ ((qr&7)<<3))] = f2bf(smat[cc][rr]);
      }
    asm volatile("s_waitcnt lgkmcnt(0)" ::: "memory");

    short8 pf0, pf1;
    {
      const int qr = r16;
      const int sw = (qr & 7) << 3;
      pf0 = *(const short8*)&Pl[wave][qr*64 + ((g4*8)      ^ sw)];
      pf1 = *(const short8*)&Pl[wave][qr*64 + ((g4*8 + 32) ^ sw)];
    }
    #pragma unroll
    for (int n=0;n<8;n++){
      const int vr = n*16 + r16;
      const int sw = (vr & 7) << 3;
      short8 vf0 = *(const short8*)&Vl[cur][vr*64 + ((g4*8)      ^ sw)];
      short8 vf1 = *(const short8*)&Vl[cur][vr*64 + ((g4*8 + 32) ^ sw)];
      o[n] = __builtin_amdgcn_mfma_f32_16x16x32_bf16(pf0, vf0, o[n], 0,0,0);
      o[n] = __builtin_amdgcn_mfma_f32_16x16x32_bf16(pf1, vf1, o[n], 0,0,0);
    }
    cur ^= 1;
  }

  {
    const size_t yr0 = (size_t)(bb*T_SEQ + qt*128 + wave*16 + g4*4) * C_DIM + h*128;
    #pragma unroll
    for (int n=0;n<8;n++)
      #pragma unroll
      for (int rr=0;rr<4;rr++){
        const float v = o[n][rr] / lrow[rr];
        y[yr0 + (size_t)rr*C_DIM + n*16 + r16] = f2bf(v);
      }
  }
}

extern "C" void kernel_launch(void* const* d_in, const int* in_sizes, int n_in,
                              void* d_out, int out_size, void* d_ws, size_t ws_size,
                              hipStream_t stream){
  const float* x  = (const float*)d_in[0];
  const float* wa = (const float*)d_in[1];
  const float* wp = (const float*)d_in[2];
  float* out = (float*)d_out;

  u16* ws  = (u16*)d_ws;
  u16* xb  = ws;                 //  8,388,608 elems (x bf16) — reused as yb later
  u16* wab = xb  + 8388608;      // 12,582,912 elems (w_attn bf16)
  u16* wpb = wab + 12582912;     //  4,194,304 elems (w_proj bf16)
  u16* qk  = wpb + 4194304;      // 16,777,216 elems ([4096][4096] Q|K)
  u16* vt  = qk  + 16777216;     //  8,388,608 elems ([32][128][2048] V^T)
  u16* yb  = xb;                 // alias: x dead after GEMM1

  hipLaunchKernelGGL(cvt3_kernel, dim3(2048), dim3(256), 0, stream,
                     x, wa, wp, xb, wab, wpb);

  // qkv projection: grid 48 n-tiles(128) x 32 m-tiles(128) = 1536 = 3 rounds @ 2/CU
  hipLaunchKernelGGL((gemm256<1,u16>),   dim3(48,32), dim3(256), 0, stream,
                     xb, wab, qk, vt, 4096, 6144, 2048);
  hipLaunchKernelGGL(attn_kernel,        dim3(512),  dim3(512), 0, stream,
                     qk, vt, yb);
  // out projection: grid 16 x 32 = 512 = 1 round @ 2/CU
  hipLaunchKernelGGL((gemm256<0,float>), dim3(16,32), dim3(256), 0, stream,
                     yb, wpb, out, (u16*)nullptr, 4096, 2048, 2048);
}

// Round 20
// 245.860 us; speedup vs baseline: 1.3624x; 1.0015x over previous
//
#include <hip/hip_runtime.h>

typedef __attribute__((ext_vector_type(8))) short short8;
typedef __attribute__((ext_vector_type(4))) float f32x4;
typedef unsigned short u16;

#define T_SEQ 2048
#define C_DIM 2048

static __device__ __forceinline__ u16 f2bf(float f){
  unsigned u = __float_as_uint(f);
  u = (u + 0x7fffu + ((u >> 16) & 1u)) >> 16;
  return (u16)u;
}

// merged f32->bf16 convert for x, w_attn, w_proj
__global__ void cvt3_kernel(const float* __restrict__ x,
                            const float* __restrict__ wa,
                            const float* __restrict__ wp,
                            u16* __restrict__ xb, u16* __restrict__ wab,
                            u16* __restrict__ wpb){
  int idx = blockIdx.x * blockDim.x + threadIdx.x;
  int stride = gridDim.x * blockDim.x;
  for (int i = idx; i < 6291456; i += stride){
    const float* src; u16* dst; int j;
    if (i < 2097152){ src = x;  dst = xb;  j = i; }
    else if (i < 5242880){ src = wa; dst = wab; j = i - 2097152; }
    else { src = wp; dst = wpb; j = i - 5242880; }
    float4 v = ((const float4*)src)[j];
    ushort4 o;
    o.x = f2bf(v.x); o.y = f2bf(v.y); o.z = f2bf(v.z); o.w = f2bf(v.w);
    ((ushort4*)dst)[j] = o;
  }
}

__device__ __forceinline__ void gl_lds16(const void* g, void* l){
  __builtin_amdgcn_global_load_lds(
      (const __attribute__((address_space(1))) unsigned int*)g,
      (__attribute__((address_space(3))) unsigned int*)l,
      16, 0, 0);
}

// ------------- 128x128 BK=64 2-phase counted-vmcnt GEMM, 2 blocks/CU --------
// r19 engine + n-fastest XCD swizzle. r20 change: DROPPED the explicit
// lgkmcnt(0)+sched_barrier(0) before each MFMA cluster — ds_read->MFMA
// ordering is a register data-dep the compiler already enforces with
// fine-grained lgkmcnt (m141 lesson: order-pinning defeats its scheduling);
// cross-wave LDS write-visibility is still guaranteed by the counted
// vmcnt + s_barrier pairs, which are unchanged.
template<int MODE, typename OUT>
__global__ __launch_bounds__(256, 2) void gemm256(const u16* __restrict__ A,
                                                  const u16* __restrict__ B,
                                                  OUT* __restrict__ C,
                                                  u16* __restrict__ VT,
                                                  int M, int N, int K){
  __shared__ __align__(16) u16 lA[2][128*64];   // 32 KB
  __shared__ __align__(16) u16 lB[2][128*64];   // 32 KB
  const int tid  = threadIdx.x;
  const int lane = tid & 63;
  const int r16  = lane & 15;
  const int g4   = lane >> 4;
  const int wave = tid >> 6;                 // 0..3
  const int wm = wave >> 1, wn = wave & 1;   // 2M x 2N

  // n-fastest XCD swizzle (bijective; gridDim.x % 8 == 0)
  const int idl = blockIdx.y * gridDim.x + blockIdx.x;
  const int xcd = idl & 7, k = idl >> 3;
  const int npx = gridDim.x >> 3;            // n-tiles per XCD
  const int bx  = xcd * npx + (k % npx);
  const int by  = k / npx;
  const int m0 = by * 128, n0 = bx * 128;

  f32x4 acc[4][4] = {};
  const int nt = K >> 6;

  auto stA = [&](int b, int t){
    #pragma unroll
    for (int c=0;c<4;c++){
      const int row0 = wave*32 + c*8;
      const int row  = row0 + (lane>>3);
      const int cole = (((lane&7) ^ (row&7)) << 3);
      gl_lds16(&A[(size_t)(m0+row)*K + t*64 + cole], &lA[b][row0*64]);
    }
  };
  auto stB2 = [&](int b, int t, int half){
    #pragma unroll
    for (int c=0;c<2;c++){
      const int row0 = (wave>>1)*64 + half*32 + (wave&1)*16 + c*8;
      const int row  = row0 + (lane>>3);
      const int cole = (((lane&7) ^ (row&7)) << 3);
      gl_lds16(&B[(size_t)(n0+row)*K + t*64 + cole], &lB[b][row0*64]);
    }
  };
  auto rdA = [&](short8 (&af)[4][2], int b){
    #pragma unroll
    for (int i=0;i<4;i++){
      const int R = wm*64 + i*16 + r16;
      #pragma unroll
      for (int ks=0;ks<2;ks++)
        af[i][ks] = *(const short8*)&lA[b][R*64 + ((g4*8 + ks*32) ^ ((R&7)<<3))];
    }
  };
  auto rdB = [&](short8 (&bf)[2][2], int b, int half){
    #pragma unroll
    for (int j=0;j<2;j++){
      const int R = wn*64 + half*32 + j*16 + r16;
      #pragma unroll
      for (int ks=0;ks<2;ks++)
        bf[j][ks] = *(const short8*)&lB[b][R*64 + ((g4*8 + ks*32) ^ ((R&7)<<3))];
    }
  };

  stA(0,0); stB2(0,0,0); stB2(0,0,1);
  asm volatile("s_waitcnt vmcnt(2)" ::: "memory");
  __builtin_amdgcn_s_barrier();
  asm volatile("" ::: "memory");

  for (int t = 0; t < nt; ++t){
    const int cb = t & 1, nb = cb ^ 1;
    const bool more = (t + 1 < nt);
    short8 af[4][2], bf[2][2];

    // ---- phase A: (A, B-low)
    rdA(af, cb); rdB(bf, cb, 0);
    if (more){
      stA(nb, t+1); stB2(nb, t+1, 0);
      asm volatile("s_waitcnt vmcnt(6)" ::: "memory");
    } else {
      asm volatile("s_waitcnt vmcnt(0)" ::: "memory");
    }
    __builtin_amdgcn_s_barrier();
    __builtin_amdgcn_s_setprio(1);
    #pragma unroll
    for (int i=0;i<4;i++)
      #pragma unroll
      for (int j=0;j<2;j++)
        #pragma unroll
        for (int ks=0;ks<2;ks++)
          acc[i][j] = __builtin_amdgcn_mfma_f32_16x16x32_bf16(af[i][ks], bf[j][ks], acc[i][j], 0,0,0);
    __builtin_amdgcn_s_setprio(0);
    __builtin_amdgcn_s_barrier();
    asm volatile("" ::: "memory");

    // ---- phase B: (A, B-high)
    rdB(bf, cb, 1);
    if (more){
      stB2(nb, t+1, 1);
      asm volatile("s_waitcnt vmcnt(2)" ::: "memory");
    }
    __builtin_amdgcn_s_barrier();
    __builtin_amdgcn_s_setprio(1);
    #pragma unroll
    for (int i=0;i<4;i++)
      #pragma unroll
      for (int j=0;j<2;j++)
        #pragma unroll
        for (int ks=0;ks<2;ks++)
          acc[i][2+j] = __builtin_amdgcn_mfma_f32_16x16x32_bf16(af[i][ks], bf[j][ks], acc[i][2+j], 0,0,0);
    __builtin_amdgcn_s_setprio(0);
    __builtin_amdgcn_s_barrier();
    asm volatile("" ::: "memory");
  }

  if (MODE == 1 && n0 >= 4096){
    #pragma unroll
    for (int i=0;i<4;i++){
      const int m = m0 + wm*64 + i*16 + g4*4;
      const int bb = m >> 11, tt = m & 2047;
      #pragma unroll
      for (int j=0;j<4;j++){
        const int cv = n0 + wn*64 + j*16 + r16 - 4096;
        const int h = cv >> 7, dl = cv & 127;
        ushort4 pack;
        pack.x = f2bf(acc[i][j][0]); pack.y = f2bf(acc[i][j][1]);
        pack.z = f2bf(acc[i][j][2]); pack.w = f2bf(acc[i][j][3]);
        *(ushort4*)&VT[(size_t)((bb<<4) + h)*262144 + (size_t)dl*2048 + tt] = pack;
      }
    }
  } else {
    const int ldc = (MODE == 1) ? 4096 : N;
    #pragma unroll
    for (int i=0;i<4;i++){
      const int row = m0 + wm*64 + i*16 + g4*4;
      #pragma unroll
      for (int j=0;j<4;j++){
        const int col = n0 + wn*64 + j*16 + r16;
        #pragma unroll
        for (int r=0;r<4;r++){
          float v = acc[i][j][r];
          if constexpr (sizeof(OUT)==2) C[(size_t)(row+r)*ldc + col] = (OUT)f2bf(v);
          else                          C[(size_t)(row+r)*ldc + col] = (OUT)v;
        }
      }
    }
  }
}

// ---------------- Flash attention: 8 waves x 16 q-rows, QBLK=128 ------------
// (round-18 verified kernel, unchanged)
__global__ __launch_bounds__(512) void attn_kernel(const u16* __restrict__ qk,
                                                   const u16* __restrict__ vt,
                                                   u16* __restrict__ y){
  __shared__ __align__(16) u16 Kl[2][64*128];   // 32 KB
  __shared__ __align__(16) u16 Vl[2][128*64];   // 32 KB
  __shared__ __align__(16) u16 Pl[8][16*64];    // 16 KB

  const int tid = threadIdx.x, lane = tid & 63, wave = tid >> 6;  // 0..7
  const int r16 = lane & 15, g4 = lane >> 4;

  const int id = blockIdx.x;            // 0..511
  const int xk = id & 7,  kk = id >> 3;
  const int bh = 4*xk + (kk & 3);       // XCD-local heads
  const int v5 = kk >> 2;               // 0..15
  const int qt = (v5 < 8) ? v5 : (23 - v5);   // (v,15-v) share a CU slot

  const int bb = bh >> 4, h = bh & 15;
  const int qcol = h*128, kcol = 2048 + h*128;
  const u16* vhead = vt + (size_t)bh * 262144;
  const float scale = 0.08838834764831845f;

  short8 qf[4];
  {
    const u16* qp = qk + (size_t)(bb*T_SEQ + qt*128 + wave*16 + r16)*4096 + qcol;
    #pragma unroll
    for (int c=0;c<4;c++) qf[c] = *(const short8*)&qp[g4*8 + c*32];
  }

  float mrow[4], lrow[4];
  #pragma unroll
  for (int r=0;r<4;r++){ mrow[r] = -1e30f; lrow[r] = 0.f; }
  f32x4 o[8] = {};

  const int nt = 2*qt + 2;

  auto stage = [&](int sbuf, int t){
    const size_t kbase = (size_t)(bb*T_SEQ + t*64)*4096 + kcol;
    #pragma unroll
    for (int c=0;c<2;c++){
      const int row0 = wave*8 + c*4;        // wave-uniform; 8 waves cover 0..63
      const int row  = row0 + g4;
      gl_lds16(&qk[kbase + (size_t)row*4096 + ((r16*8) ^ ((row&7)<<3))],
               &Kl[sbuf][row0*128]);
    }
    const int t0 = t*64;
    #pragma unroll
    for (int c=0;c<2;c++){
      const int idx = wave*2 + c;           // 0..15, wave-uniform
      const int d   = idx*8 + (lane>>3);
      const int j8  = (lane&7)*8;
      gl_lds16(&vhead[(size_t)d*2048 + t0 + (j8 ^ ((d&7)<<3))],
               &Vl[sbuf][idx*512]);
    }
  };

  stage(0, 0);
  int cur = 0;

  for (int t = 0; t < nt; ++t){
    __syncthreads();
    if (t + 1 < nt) stage(cur^1, t+1);

    // ---- S = Q K^T : per wave 16q x 64kv
    float smat[4][4];
    #pragma unroll
    for (int cc=0;cc<4;cc++){
      const int krow = cc*16 + r16;
      const int sw = (krow & 7) << 3;
      short8 kf[4];
      #pragma unroll
      for (int dc=0;dc<4;dc++)
        kf[dc] = *(const short8*)&Kl[cur][krow*128 + ((g4*8 + dc*32) ^ sw)];
      f32x4 sv = {0.f,0.f,0.f,0.f};
      #pragma unroll
      for (int dc=0;dc<4;dc++)
        sv = __builtin_amdgcn_mfma_f32_16x16x32_bf16(qf[dc], kf[dc], sv, 0,0,0);
      #pragma unroll
      for (int rr=0;rr<4;rr++) smat[cc][rr] = sv[rr] * scale;
    }
    if (t >= 2*qt){   // diagonal region (block-uniform)
      #pragma unroll
      for (int cc=0;cc<4;cc++){
        const int kvl = (t - 2*qt)*64 + cc*16 + r16;
        #pragma unroll
        for (int rr=0;rr<4;rr++){
          const int qi = wave*16 + g4*4 + rr;
          if (kvl > qi) smat[cc][rr] = -1e30f;
        }
      }
    }

    // ---- defer-max softmax (local pre-check; wave-uniform branch)
    float lm[4];
    #pragma unroll
    for (int rr=0;rr<4;rr++)
      lm[rr] = fmaxf(fmaxf(smat[0][rr], smat[1][rr]), fmaxf(smat[2][rr], smat[3][rr]));
    bool need = false;
    #pragma unroll
    for (int rr=0;rr<4;rr++) need = need || (lm[rr] > mrow[rr] + 8.f);
    if (__any(need)){
      #pragma unroll
      for (int rr=0;rr<4;rr++){
        float pmv = lm[rr];
        #pragma unroll
        for (int off=1; off<16; off<<=1) pmv = fmaxf(pmv, __shfl_xor(pmv, off, 64));
        const float mnew = fmaxf(mrow[rr], pmv);
        const float corr = __expf(mrow[rr] - mnew);
        mrow[rr] = mnew;
        lrow[rr] *= corr;
        #pragma unroll
        for (int n=0;n<8;n++) o[n][rr] *= corr;
      }
    }
    #pragma unroll
    for (int rr=0;rr<4;rr++){
      float s0 = 0.f;
      #pragma unroll
      for (int cc=0;cc<4;cc++){
        const float p = __expf(smat[cc][rr] - mrow[rr]);
        smat[cc][rr] = p;
        s0 += p;
      }
      #pragma unroll
      for (int off=1; off<16; off<<=1) s0 += __shfl_xor(s0, off, 64);
      lrow[rr] += s0;
    }

    // ---- P -> LDS (wave-local 16 rows)
    #pragma unroll
    for (int cc=0;cc<4;cc++)
      #pragma unroll
      for (int rr=0;rr<4;rr++){
        const int qr = g4*4 + rr;
        Pl[wave][qr*64 + ((cc*16 + r16) ^ ((qr&7)<<3))] = f2bf(smat[cc][rr]);
      }
    asm volatile("s_waitcnt lgkmcnt(0)" ::: "memory");

    short8 pf0, pf1;
    {
      const int qr = r16;
      const int sw = (qr & 7) << 3;
      pf0 = *(const short8*)&Pl[wave][qr*64 + ((g4*8)      ^ sw)];
      pf1 = *(const short8*)&Pl[wave][qr*64 + ((g4*8 + 32) ^ sw)];
    }
    #pragma unroll
    for (int n=0;n<8;n++){
      const int vr = n*16 + r16;
      const int sw = (vr & 7) << 3;
      short8 vf0 = *(const short8*)&Vl[cur][vr*64 + ((g4*8)      ^ sw)];
      short8 vf1 = *(const short8*)&Vl[cur][vr*64 + ((g4*8 + 32) ^ sw)];
      o[n] = __builtin_amdgcn_mfma_f32_16x16x32_bf16(pf0, vf0, o[n], 0,0,0);
      o[n] = __builtin_amdgcn_mfma_f32_16x16x32_bf16(pf1, vf1, o[n], 0,0,0);
    }
    cur ^= 1;
  }

  {
    const size_t yr0 = (size_t)(bb*T_SEQ + qt*128 + wave*16 + g4*4) * C_DIM + h*128;
    #pragma unroll
    for (int n=0;n<8;n++)
      #pragma unroll
      for (int rr=0;rr<4;rr++){
        const float v = o[n][rr] / lrow[rr];
        y[yr0 + (size_t)rr*C_DIM + n*16 + r16] = f2bf(v);
      }
  }
}

extern "C" void kernel_launch(void* const* d_in, const int* in_sizes, int n_in,
                              void* d_out, int out_size, void* d_ws, size_t ws_size,
                              hipStream_t stream){
  const float* x  = (const float*)d_in[0];
  const float* wa = (const float*)d_in[1];
  const float* wp = (const float*)d_in[2];
  float* out = (float*)d_out;

  u16* ws  = (u16*)d_ws;
  u16* xb  = ws;                 //  8,388,608 elems (x bf16) — reused as yb later
  u16* wab = xb  + 8388608;      // 12,582,912 elems (w_attn bf16)
  u16* wpb = wab + 12582912;     //  4,194,304 elems (w_proj bf16)
  u16* qk  = wpb + 4194304;      // 16,777,216 elems ([4096][4096] Q|K)
  u16* vt  = qk  + 16777216;     //  8,388,608 elems ([32][128][2048] V^T)
  u16* yb  = xb;                 // alias: x dead after GEMM1

  hipLaunchKernelGGL(cvt3_kernel, dim3(2048), dim3(256), 0, stream,
                     x, wa, wp, xb, wab, wpb);

  // qkv projection: grid 48 n-tiles(128) x 32 m-tiles(128) = 1536 = 3 rounds @ 2/CU
  hipLaunchKernelGGL((gemm256<1,u16>),   dim3(48,32), dim3(256), 0, stream,
                     xb, wab, qk, vt, 4096, 6144, 2048);
  hipLaunchKernelGGL(attn_kernel,        dim3(512),  dim3(512), 0, stream,
                     qk, vt, yb);
  // out projection: grid 16 x 32 = 512 = 1 round @ 2/CU
  hipLaunchKernelGGL((gemm256<0,float>), dim3(16,32), dim3(256), 0, stream,
                     yb, wpb, out, (u16*)nullptr, 4096, 2048, 2048);
}